// Round 11
// baseline (131.331 us; speedup 1.0000x reference)
//
#include <hip/hip_runtime.h>

#define TSIZE 512
#define NT 512
#define EPSV 1e-9f
#define NPIX (TSIZE * TSIZE)

// ATTRIBUTION ROUND: identical kernels to round 10; render_main launched 3x
// (idempotent) so dur = base + 2*main_cost resolves main's true cost.
//
// masks : per-(row, 64j-strip) 512-bit survivor bitmask + records/ybnd/zmin.
// main  : 512 thr/block = 256 pixels x 2 tri-chunks; uniform ctz pop loop,
//         scalar record loads, (zb,t_win) tracking, LDS lex-merge, one interp.

__device__ __forceinline__ float rcp_fast(float x) {
  float r;
  asm("v_rcp_f32 %0, %1" : "=v"(r) : "v"(x));
  return r;
}

// ---------------- masks (+ block0: records, ybnd, zmin) ----------------
__global__ __launch_bounds__(256) void render_masks(const float* __restrict__ tris,
                                                    unsigned long long* __restrict__ masks,
                                                    float* __restrict__ recs,
                                                    unsigned* __restrict__ ybnd,
                                                    float* __restrict__ zminp) {
  __shared__ float4 raw[1152];
  __shared__ float ska[NT * 12];
  __shared__ uint2 sbn[NT];
  __shared__ float sred[4];

  const int tid = threadIdx.x;
  {
    const float4* g4 = (const float4*)tris;
#pragma unroll
    for (int k = 0; k < 5; ++k) {
      int idx = tid + 256 * k;
      if (idx < 1152) raw[idx] = g4[idx];
    }
  }
  __syncthreads();
  const float* rawf = (const float*)raw;
  const bool isb0 = (blockIdx.x == 0);
  float zp = 3.4e38f;
#pragma unroll
  for (int q = 0; q < 2; ++q) {
    const int t = 2 * tid + q;
    const float* tp = rawf + t * 9;
    float v0x = tp[0], v0y = tp[1], v0z = tp[2];
    float v1x = tp[3], v1y = tp[4], v1z = tp[5];
    float v2x = tp[6], v2y = tp[7], v2z = tp[8];
    float w = __fsub_rn(__fmul_rn(__fsub_rn(v1x, v0x), __fsub_rn(v2y, v0y)),
                        __fmul_rn(__fsub_rn(v1y, v0y), __fsub_rn(v2x, v0x)));
    bool valid = (w >= EPSV);
    float r2  = __fsub_rn(v0y, v1y), r3  = __fsub_rn(v0x, v1x);
    float r6  = __fsub_rn(v1y, v2y), r7  = __fsub_rn(v1x, v2x);
    float r10 = __fsub_rn(v2y, v0y), r11 = __fsub_rn(v2x, v0x);
    float* ka = &ska[t * 12];
    ka[0] = r2;   ka[1] = -r3;   ka[2] = v1y * r3 - v1x * r2;
    ka[3] = r6;   ka[4] = -r7;   ka[5] = v2y * r7 - v2x * r6;
    ka[6] = r10;  ka[7] = -r11;  ka[8] = v0y * r11 - v0x * r10;
    int xmn = 0, xmx = 0, ymn = 0, ymx = 0;
    if (valid) {
      float bxn = fminf(v0x, fminf(v1x, v2x));
      float byn = fminf(v0y, fminf(v1y, v2y));
      float bxx = fmaxf(v0x, fmaxf(v1x, v2x));
      float byx = fmaxf(v0y, fmaxf(v1y, v2y));
      xmn = (int)floorf(__fmul_rn(__fadd_rn(fminf(fmaxf(bxn, -1.0f), 1.0f), 1.0f), 256.0f));
      ymn = (int)floorf(__fmul_rn(__fadd_rn(fminf(fmaxf(byn, -1.0f), 1.0f), 1.0f), 256.0f));
      xmx = (int)floorf(__fmul_rn(__fadd_rn(fminf(fmaxf(bxx, -1.0f), 1.0f), 1.0f), 256.0f));
      ymx = (int)floorf(__fmul_rn(__fadd_rn(fminf(fmaxf(byx, -1.0f), 1.0f), 1.0f), 256.0f));
    }
    sbn[t] = make_uint2((unsigned)xmn | ((unsigned)xmx << 16),
                        (unsigned)ymn | ((unsigned)ymx << 16));
    if (isb0) {
      zp = fminf(zp, fminf(v0z, fminf(v1z, v2z)));
      float ws = valid ? w : 1.0f;
      float4* g = (float4*)(recs + ((size_t)t << 4));
      g[0] = make_float4(v1x, v1y, r2, r3);
      g[1] = make_float4(v2x, v2y, r6, r7);
      g[2] = make_float4(v0x, v0y, r10, r11);
      g[3] = make_float4(__fdiv_rn(1.0f, ws), v2z,
                         __fsub_rn(v0z, v2z), __fsub_rn(v1z, v2z));
      ybnd[t] = (unsigned)ymn | ((unsigned)ymx << 16);
    }
  }
  if (isb0) {
    for (int off = 32; off > 0; off >>= 1) zp = fminf(zp, __shfl_down(zp, off, 64));
    if ((tid & 63) == 0) sred[tid >> 6] = zp;
  }
  __syncthreads();
  if (isb0 && tid == 0) {
    zminp[0] = fminf(fminf(sred[0], sred[1]), fminf(sred[2], sred[3]));
  }

  const int s = blockIdx.x * 32 + (tid & 31);
  const int w = tid >> 5;
  const int i = s >> 3;
  const unsigned jw0 = (unsigned)((s & 7) << 6);
  const float delta = 2.0f / 511.0f;
  const float px  = -1.0f + (float)i * delta;
  const float pyL = -1.0f + (float)jw0 * delta;
  const float pyR = -1.0f + (float)(jw0 + 63u) * delta;

  unsigned long long m = 0;
#pragma unroll 4
  for (int b = 0; b < 64; ++b) {
    const int t = (w << 6) + b;
    uint2 bw = sbn[t];
    unsigned xm = bw.x & 0xFFFFu, xM = bw.x >> 16;
    unsigned ym = bw.y & 0xFFFFu, yM = bw.y >> 16;
    bool pass = ((unsigned)i >= xm) & ((unsigned)i < xM) &
                (ym < jw0 + 64u) & (yM > jw0);
    if (pass) {
      const float4* ka4 = (const float4*)&ska[t * 12];
      float4 e01 = ka4[0];
      float4 e12 = ka4[1];
      float4 e2k = ka4[2];
      float ylo = -1e30f, yhi = 1e30f;
      {
        float S = e01.y, c = e01.z + e01.x * px;
        if (S > 1e-20f)       { float cd = -c * rcp_fast(S); ylo = fmaxf(ylo, cd - (0.005f + 4e-6f * fabsf(cd))); }
        else if (S < -1e-20f) { float cd = -c * rcp_fast(S); yhi = fminf(yhi, cd + (0.005f + 4e-6f * fabsf(cd))); }
      }
      {
        float S = e12.x, c = e12.y + e01.w * px;
        if (S > 1e-20f)       { float cd = -c * rcp_fast(S); ylo = fmaxf(ylo, cd - (0.005f + 4e-6f * fabsf(cd))); }
        else if (S < -1e-20f) { float cd = -c * rcp_fast(S); yhi = fminf(yhi, cd + (0.005f + 4e-6f * fabsf(cd))); }
      }
      {
        float S = e12.w, c = e2k.x + e12.z * px;
        if (S > 1e-20f)       { float cd = -c * rcp_fast(S); ylo = fmaxf(ylo, cd - (0.005f + 4e-6f * fabsf(cd))); }
        else if (S < -1e-20f) { float cd = -c * rcp_fast(S); yhi = fminf(yhi, cd + (0.005f + 4e-6f * fabsf(cd))); }
      }
      pass = (ylo <= pyR) & (yhi >= pyL);
    }
    m |= ((unsigned long long)(pass ? 1 : 0)) << b;
  }
  masks[(size_t)s * 8 + w] = m;
}

// ---------------- main ----------------
#define EVAL_T(rp, yb, tt)                                                        \
  do {                                                                            \
    float v1x = (rp)[0], v1y = (rp)[1], r2 = (rp)[2], r3 = (rp)[3];               \
    float v2x = (rp)[4], v2y = (rp)[5], r6 = (rp)[6], r7 = (rp)[7];               \
    float v0x = (rp)[8], v0y = (rp)[9], r10 = (rp)[10], r11 = (rp)[11];           \
    float rw_ = (rp)[12], v2z = (rp)[13], d0z = (rp)[14], d1z = (rp)[15];         \
    float pAB = __fsub_rn(__fmul_rn(__fsub_rn(px, v1x), r2),                      \
                          __fmul_rn(__fsub_rn(py, v1y), r3));                     \
    float pCB = __fsub_rn(__fmul_rn(__fsub_rn(px, v2x), r6),                      \
                          __fmul_rn(__fsub_rn(py, v2y), r7));                     \
    float pCA = __fsub_rn(__fmul_rn(__fsub_rn(px, v0x), r10),                     \
                          __fmul_rn(__fsub_rn(py, v0y), r11));                    \
    bool ins = (pAB > 0.0f) & (pCB > 0.0f) & (pCA > 0.0f) &                       \
               (ju >= ((yb) & 0xFFFFu)) & (ju < ((yb) >> 16));                    \
    float w1 = __fmul_rn(pCB, rw_);                                               \
    float w2 = __fmul_rn(pCA, rw_);                                               \
    float pz = __fmaf_rn(w1, d0z, __fmaf_rn(w2, d1z, v2z));                       \
    bool mk = ins & (pz >= zb);                                                   \
    zb = mk ? pz : zb;                                                            \
    tw = mk ? (tt) : tw;                                                          \
  } while (0)

__global__ __launch_bounds__(512) void render_main(const float* __restrict__ recs,
                                                   const unsigned* __restrict__ ybnd,
                                                   const unsigned long long* __restrict__ masks,
                                                   const float* __restrict__ zminp,
                                                   float4* __restrict__ out) {
  __shared__ float2 smrg[512];

  const int tid = threadIdx.x;
  const int pix = tid & 255;
  const int chunk = tid >> 8;
  const int bb = blockIdx.x;
  const int i = bb >> 1;
  const int j = ((bb & 1) << 8) | pix;
  const unsigned ju = (unsigned)j;
  const float delta = 2.0f / 511.0f;
  const float px = __fadd_rn(-1.0f, __fmul_rn((float)i, delta));
  const float py = __fadd_rn(-1.0f, __fmul_rn((float)j, delta));

  const int jstrip = __builtin_amdgcn_readfirstlane(pix >> 6);
  const unsigned long long* mp =
      masks + ((size_t)(i << 3) + ((bb & 1) << 2) + jstrip) * 8 + chunk * 4;
  unsigned long long m4[4];
#pragma unroll
  for (int k = 0; k < 4; ++k) m4[k] = mp[k];

  float zb = zminp[0];
  int tw = -1;

#pragma unroll 1
  for (int w = 0; w < 4; ++w) {
    unsigned long long m = m4[w];
    const int base = (chunk * 4 + w) << 6;
    while (m) {
      int t0 = base + __builtin_ctzll(m); m &= m - 1;
      t0 = __builtin_amdgcn_readfirstlane(t0);
      int t1 = -1, t2 = -1;
      if (m) {
        t1 = base + __builtin_ctzll(m); m &= m - 1;
        t1 = __builtin_amdgcn_readfirstlane(t1);
        if (m) {
          t2 = base + __builtin_ctzll(m); m &= m - 1;
          t2 = __builtin_amdgcn_readfirstlane(t2);
        }
      }
      const float* r0 = recs + ((size_t)t0 << 4);
      const unsigned y0 = ybnd[t0];
      EVAL_T(r0, y0, t0);
      if (t1 >= 0) {
        const float* r1 = recs + ((size_t)t1 << 4);
        const unsigned y1 = ybnd[t1];
        EVAL_T(r1, y1, t1);
      }
      if (t2 >= 0) {
        const float* r2p = recs + ((size_t)t2 << 4);
        const unsigned y2 = ybnd[t2];
        EVAL_T(r2p, y2, t2);
      }
    }
  }

  smrg[tid] = make_float2(zb, __int_as_float(tw));
  __syncthreads();

  if (tid < 256) {
    float2 a = smrg[tid];
    float2 b = smrg[tid + 256];
    int t0 = __float_as_int(a.y), t1 = __float_as_int(b.y);
    bool win1 = (b.x > a.x) | ((b.x == a.x) & (t1 > t0));
    int twf = win1 ? t1 : t0;
    float zf = win1 ? b.x : a.x;

    float4 res = make_float4(0.0f, 0.0f, 0.0f, 0.0f);
    if (twf >= 0) {
      const float4* rr = (const float4*)(recs + ((size_t)twf << 4));
      float4 f1 = rr[1];
      float4 f2 = rr[2];
      float4 f3 = rr[3];
      float pCB = __fsub_rn(__fmul_rn(__fsub_rn(px, f1.x), f1.z),
                            __fmul_rn(__fsub_rn(py, f1.y), f1.w));
      float pCA = __fsub_rn(__fmul_rn(__fsub_rn(px, f2.x), f2.z),
                            __fmul_rn(__fsub_rn(py, f2.y), f2.w));
      float w1 = __fmul_rn(pCB, f3.x);
      float w2 = __fmul_rn(pCA, f3.x);
      float rx = __fmaf_rn(w1, -f2.w, __fmaf_rn(w2, f1.w, f1.x));
      float ry = __fmaf_rn(w1, -f2.z, __fmaf_rn(w2, f1.z, f1.y));
      res = make_float4(rx, ry, zf, 1.0f);
    }
    out[(i << 9) | j] = res;
  }
}

// ---- last-resort fallback (round-2 single kernel, no ws) ----
__global__ __launch_bounds__(256) void render_fallback(const float* __restrict__ tris,
                                                       float4* __restrict__ out) {
  __shared__ float sf[10 * NT];
  __shared__ unsigned short sb[4 * NT];
  __shared__ float s_zred[4];
  const int tid = threadIdx.x;
  for (int t = tid; t < NT; t += 256) {
    const float* tp = tris + t * 9;
    float v0x = tp[0], v0y = tp[1], v0z = tp[2];
    float v1x = tp[3], v1y = tp[4], v1z = tp[5];
    float v2x = tp[6], v2y = tp[7], v2z = tp[8];
    sf[0*NT+t] = v0x; sf[1*NT+t] = v0y; sf[2*NT+t] = v0z;
    sf[3*NT+t] = v1x; sf[4*NT+t] = v1y; sf[5*NT+t] = v1z;
    sf[6*NT+t] = v2x; sf[7*NT+t] = v2y; sf[8*NT+t] = v2z;
    float w = __fsub_rn(__fmul_rn(__fsub_rn(v1x,v0x), __fsub_rn(v2y,v0y)),
                        __fmul_rn(__fsub_rn(v1y,v0y), __fsub_rn(v2x,v0x)));
    bool valid = (w >= EPSV);
    sf[9*NT+t] = valid ? w : 1.0f;
    int xmn = 0, xmx = 0, ymn = 0, ymx = 0;
    if (valid) {
      float bxn = fminf(v0x, fminf(v1x, v2x));
      float byn = fminf(v0y, fminf(v1y, v2y));
      float bxx = fmaxf(v0x, fmaxf(v1x, v2x));
      float byx = fmaxf(v0y, fmaxf(v1y, v2y));
      xmn = (int)floorf(__fmul_rn(__fadd_rn(fminf(fmaxf(bxn,-1.0f),1.0f),1.0f),256.0f));
      ymn = (int)floorf(__fmul_rn(__fadd_rn(fminf(fmaxf(byn,-1.0f),1.0f),1.0f),256.0f));
      xmx = (int)floorf(__fmul_rn(__fadd_rn(fminf(fmaxf(bxx,-1.0f),1.0f),1.0f),256.0f));
      ymx = (int)floorf(__fmul_rn(__fadd_rn(fminf(fmaxf(byx,-1.0f),1.0f),1.0f),256.0f));
    }
    sb[0*NT+t] = (unsigned short)xmn; sb[1*NT+t] = (unsigned short)xmx;
    sb[2*NT+t] = (unsigned short)ymn; sb[3*NT+t] = (unsigned short)ymx;
  }
  float zm = 3.4e38f;
  for (int v = tid; v < NT * 3; v += 256) zm = fminf(zm, tris[v * 3 + 2]);
  for (int off = 32; off > 0; off >>= 1) zm = fminf(zm, __shfl_down(zm, off, 64));
  if ((tid & 63) == 0) s_zred[tid >> 6] = zm;
  __syncthreads();
  zm = fminf(fminf(s_zred[0], s_zred[1]), fminf(s_zred[2], s_zred[3]));
  const int pid = blockIdx.x * 256 + tid;
  const int i = pid >> 9;
  const int j = pid & (TSIZE - 1);
  const float delta = 2.0f / 511.0f;
  const float px = __fadd_rn(-1.0f, __fmul_rn((float)i, delta));
  const float py = __fadd_rn(-1.0f, __fmul_rn((float)j, delta));
  float zb = zm, rx = 0.0f, ry = 0.0f, rz = 0.0f, ra = 0.0f;
  for (int t = 0; t < NT; ++t) {
    int xmn = sb[0*NT+t], xmx = sb[1*NT+t];
    int ymn = sb[2*NT+t], ymx = sb[3*NT+t];
    if (i < xmn || i >= xmx || j < ymn || j >= ymx) continue;
    float v0x = sf[0*NT+t], v0y = sf[1*NT+t];
    float v1x = sf[3*NT+t], v1y = sf[4*NT+t];
    float v2x = sf[6*NT+t], v2y = sf[7*NT+t];
    float pAB = __fsub_rn(__fmul_rn(__fsub_rn(px,v1x), __fsub_rn(v0y,v1y)),
                          __fmul_rn(__fsub_rn(py,v1y), __fsub_rn(v0x,v1x)));
    float pCB = __fsub_rn(__fmul_rn(__fsub_rn(px,v2x), __fsub_rn(v1y,v2y)),
                          __fmul_rn(__fsub_rn(py,v2y), __fsub_rn(v1x,v2x)));
    float pCA = __fsub_rn(__fmul_rn(__fsub_rn(px,v0x), __fsub_rn(v2y,v0y)),
                          __fmul_rn(__fsub_rn(py,v0y), __fsub_rn(v2x,v0x)));
    float prod = __fmul_rn(__fmul_rn(fmaxf(pAB,0.0f), fmaxf(pCB,0.0f)), fmaxf(pCA,0.0f));
    if (prod > 0.0f) {
      float ws = sf[9*NT+t];
      float w1 = __fdiv_rn(pCB, ws);
      float w2 = __fdiv_rn(pCA, ws);
      float w3 = __fsub_rn(__fsub_rn(1.0f, w1), w2);
      float v0z = sf[2*NT+t], v1z = sf[5*NT+t], v2z = sf[8*NT+t];
      float pz = __fadd_rn(__fadd_rn(__fmul_rn(w1,v0z), __fmul_rn(w2,v1z)),
                           __fmul_rn(w3,v2z));
      if (pz >= zb) {
        zb = pz;
        rx = __fadd_rn(__fadd_rn(__fmul_rn(w1,v0x), __fmul_rn(w2,v1x)),
                       __fmul_rn(w3,v2x));
        ry = __fadd_rn(__fadd_rn(__fmul_rn(w1,v0y), __fmul_rn(w2,v1y)),
                       __fmul_rn(w3,v2y));
        rz = pz; ra = 1.0f;
      }
    }
  }
  out[pid] = make_float4(rx, ry, rz, ra);
}

extern "C" void kernel_launch(void* const* d_in, const int* in_sizes, int n_in,
                              void* d_out, int out_size, void* d_ws, size_t ws_size,
                              hipStream_t stream) {
  const float* tris = (const float*)d_in[0];
  float4* out = (float4*)d_out;
  const size_t REC_B  = (size_t)NT * 64;
  const size_t YB_B   = (size_t)NT * 4;
  const size_t MASK_B = (size_t)4096 * 8 * 8;
  const size_t ZMIN_B = 64;
  const size_t NEED = REC_B + YB_B + MASK_B + ZMIN_B;

  if (ws_size >= NEED) {
    float* recs = (float*)d_ws;
    unsigned* ybnd = (unsigned*)((char*)d_ws + REC_B);
    unsigned long long* masks = (unsigned long long*)((char*)d_ws + REC_B + YB_B);
    float* zminp = (float*)((char*)d_ws + REC_B + YB_B + MASK_B);
    hipLaunchKernelGGL(render_masks, dim3(128), dim3(256), 0, stream,
                       tris, masks, recs, ybnd, zminp);
    // ATTRIBUTION: main launched 3x (idempotent). dur = base + 2*main_cost.
    hipLaunchKernelGGL(render_main, dim3(1024), dim3(512), 0, stream,
                       recs, ybnd, masks, zminp, out);
    hipLaunchKernelGGL(render_main, dim3(1024), dim3(512), 0, stream,
                       recs, ybnd, masks, zminp, out);
    hipLaunchKernelGGL(render_main, dim3(1024), dim3(512), 0, stream,
                       recs, ybnd, masks, zminp, out);
  } else {
    hipLaunchKernelGGL(render_fallback, dim3((TSIZE * TSIZE) / 256), dim3(256), 0, stream,
                       tris, out);
  }
}

// Round 12
// 78.489 us; speedup vs baseline: 1.6732x; 1.6732x over previous
//
#include <hip/hip_runtime.h>

#define TSIZE 512
#define NT 512
#define EPSV 1e-9f

// SINGLE fused kernel. Grid = 4096 blocks (one per (row i, 64j-strip)),
// 512 threads = 8 waves.
//  1. stage raw tris (18 KB) into LDS.
//  2. thread t computes tri t's record (R4 layout) into LDS + this strip's
//     cull test (exact AABB ints + conservative slice y-interval, identical
//     to the old masks kernel) -> __ballot = wave w's survivor word for tris
//     [64w, 64w+64) held in an SGPR. zmin reduced in-block.
//  3. wave w pops its word (uniform SALU ctz), evals survivors for its 64
//     pixels (lane = pixel) from LDS broadcast reads, tracks (zb, t_win).
//  4. 8-way lex-merge (painter == lex-argmax(pz,t), R7-validated) by wave 0,
//     one exact winner interpolation, coalesced 64-pixel store.
// No workspace needed. Sign-determining chains bit-exact vs numpy
// (__f*_rn, same order, same single-rounded diffs as R4..R11); cull math is
// conservative-only; interp/z-test deviations value-only.

__device__ __forceinline__ float rcp_fast(float x) {
  float r;
  asm("v_rcp_f32 %0, %1" : "=v"(r) : "v"(x));
  return r;
}

__global__ __launch_bounds__(512) void render_fused(const float* __restrict__ tris,
                                                    float4* __restrict__ out) {
  __shared__ float4 lrec[NT * 4];   // 32 KB records; first 18 KB doubles as raw stage
  __shared__ unsigned lbY[NT];      // 2 KB ym|yM<<16
  __shared__ float2 smrg[NT];       // 4 KB merge (8 waves x 64 lanes)
  __shared__ float sred[8];

  const int tid = threadIdx.x;      // 0..511
  const int s = blockIdx.x;         // strip id 0..4095
  const int i = s >> 3;             // row (block-uniform)
  const unsigned jw0 = (unsigned)((s & 7) << 6);
  const float delta = 2.0f / 511.0f;

  // ---- 1. stage raw tris ----
  {
    const float4* g4 = (const float4*)tris;
    float4* rw4 = lrec;
    rw4[tid] = g4[tid];
    rw4[tid + 512] = g4[tid + 512];
    int i3 = tid + 1024;
    if (i3 < 1152) rw4[i3] = g4[i3];
  }
  __syncthreads();

  // ---- 2. per-tri record + cull for THIS strip ----
  const float* rawf = (const float*)lrec;
  const float* tp = rawf + tid * 9;
  float v0x = tp[0], v0y = tp[1], v0z = tp[2];
  float v1x = tp[3], v1y = tp[4], v1z = tp[5];
  float v2x = tp[6], v2y = tp[7], v2z = tp[8];
  __syncthreads();   // all raw reads in registers -> safe to overwrite

  float w = __fsub_rn(__fmul_rn(__fsub_rn(v1x, v0x), __fsub_rn(v2y, v0y)),
                      __fmul_rn(__fsub_rn(v1y, v0y), __fsub_rn(v2x, v0x)));
  bool valid = (w >= EPSV);
  float ws = valid ? w : 1.0f;
  float r2  = __fsub_rn(v0y, v1y), r3  = __fsub_rn(v0x, v1x);
  float r6  = __fsub_rn(v1y, v2y), r7  = __fsub_rn(v1x, v2x);
  float r10 = __fsub_rn(v2y, v0y), r11 = __fsub_rn(v2x, v0x);

  int xmn = 0, xmx = 0, ymn = 0, ymx = 0;
  if (valid) {
    float bxn = fminf(v0x, fminf(v1x, v2x));
    float byn = fminf(v0y, fminf(v1y, v2y));
    float bxx = fmaxf(v0x, fmaxf(v1x, v2x));
    float byx = fmaxf(v0y, fmaxf(v1y, v2y));
    xmn = (int)floorf(__fmul_rn(__fadd_rn(fminf(fmaxf(bxn, -1.0f), 1.0f), 1.0f), 256.0f));
    ymn = (int)floorf(__fmul_rn(__fadd_rn(fminf(fmaxf(byn, -1.0f), 1.0f), 1.0f), 256.0f));
    xmx = (int)floorf(__fmul_rn(__fadd_rn(fminf(fmaxf(bxx, -1.0f), 1.0f), 1.0f), 256.0f));
    ymx = (int)floorf(__fmul_rn(__fadd_rn(fminf(fmaxf(byx, -1.0f), 1.0f), 1.0f), 256.0f));
  }

  bool pass = ((unsigned)i >= (unsigned)xmn) & ((unsigned)i < (unsigned)xmx) &
              ((unsigned)ymn < jw0 + 64u) & ((unsigned)ymx > jw0);
  if (pass) {
    const float px_s = -1.0f + (float)i * delta;
    const float pyL = -1.0f + (float)jw0 * delta;
    const float pyR = -1.0f + (float)(jw0 + 63u) * delta;
    float ylo = -1e30f, yhi = 1e30f;
    {
      float S = -r3, c = (v1y * r3 - v1x * r2) + r2 * px_s;
      if (S > 1e-20f)       { float cd = -c * rcp_fast(S); ylo = fmaxf(ylo, cd - (0.005f + 4e-6f * fabsf(cd))); }
      else if (S < -1e-20f) { float cd = -c * rcp_fast(S); yhi = fminf(yhi, cd + (0.005f + 4e-6f * fabsf(cd))); }
    }
    {
      float S = -r7, c = (v2y * r7 - v2x * r6) + r6 * px_s;
      if (S > 1e-20f)       { float cd = -c * rcp_fast(S); ylo = fmaxf(ylo, cd - (0.005f + 4e-6f * fabsf(cd))); }
      else if (S < -1e-20f) { float cd = -c * rcp_fast(S); yhi = fminf(yhi, cd + (0.005f + 4e-6f * fabsf(cd))); }
    }
    {
      float S = -r11, c = (v0y * r11 - v0x * r10) + r10 * px_s;
      if (S > 1e-20f)       { float cd = -c * rcp_fast(S); ylo = fmaxf(ylo, cd - (0.005f + 4e-6f * fabsf(cd))); }
      else if (S < -1e-20f) { float cd = -c * rcp_fast(S); yhi = fminf(yhi, cd + (0.005f + 4e-6f * fabsf(cd))); }
    }
    pass = (ylo <= pyR) & (yhi >= pyL);
  }
  const unsigned long long word = __ballot(pass ? 1 : 0);  // wave w: tris [64w,64w+64)

  lrec[tid * 4 + 0] = make_float4(v1x, v1y, r2, r3);
  lrec[tid * 4 + 1] = make_float4(v2x, v2y, r6, r7);
  lrec[tid * 4 + 2] = make_float4(v0x, v0y, r10, r11);
  lrec[tid * 4 + 3] = make_float4(__fdiv_rn(1.0f, ws), v2z,
                                  __fsub_rn(v0z, v2z), __fsub_rn(v1z, v2z));
  lbY[tid] = (unsigned)ymn | ((unsigned)ymx << 16);

  float zp = fminf(v0z, fminf(v1z, v2z));
  for (int off = 32; off > 0; off >>= 1) zp = fminf(zp, __shfl_down(zp, off, 64));
  if ((tid & 63) == 0) sred[tid >> 6] = zp;
  __syncthreads();
  float zm0 = sred[0];
#pragma unroll
  for (int k = 1; k < 8; ++k) zm0 = fminf(zm0, sred[k]);

  // ---- 3. eval: wave w pops its word; lane = pixel ----
  const int lane = tid & 63;
  const int base = tid & ~63;                 // = (wave)<<6 in tri space
  const unsigned ju = jw0 + (unsigned)lane;
  const float px = __fadd_rn(-1.0f, __fmul_rn((float)i, delta));
  const float py = __fadd_rn(-1.0f, __fmul_rn((float)ju, delta));

  float zb = zm0;
  int tw = -1;
  unsigned long long m = word;
  while (m) {
    const int t = base + __builtin_ctzll(m);
    m &= m - 1;
    float4 c0 = lrec[t * 4 + 0];
    float4 c1 = lrec[t * 4 + 1];
    float4 c2 = lrec[t * 4 + 2];
    float4 c3 = lrec[t * 4 + 3];
    unsigned yb = lbY[t];
    float pAB = __fsub_rn(__fmul_rn(__fsub_rn(px, c0.x), c0.z),
                          __fmul_rn(__fsub_rn(py, c0.y), c0.w));
    float pCB = __fsub_rn(__fmul_rn(__fsub_rn(px, c1.x), c1.z),
                          __fmul_rn(__fsub_rn(py, c1.y), c1.w));
    float pCA = __fsub_rn(__fmul_rn(__fsub_rn(px, c2.x), c2.z),
                          __fmul_rn(__fsub_rn(py, c2.y), c2.w));
    bool ins = (pAB > 0.0f) & (pCB > 0.0f) & (pCA > 0.0f) &
               (ju >= (yb & 0xFFFFu)) & (ju < (yb >> 16));
    float w1 = __fmul_rn(pCB, c3.x);
    float w2 = __fmul_rn(pCA, c3.x);
    float pz = __fmaf_rn(w1, c3.z, __fmaf_rn(w2, c3.w, c3.y));
    bool mk = ins & (pz >= zb);
    zb = mk ? pz : zb;
    tw = mk ? t : tw;
  }
  smrg[tid] = make_float2(zb, __int_as_float(tw));
  __syncthreads();

  // ---- 4. 8-way lex-merge + winner interp (wave 0) ----
  if (tid < 64) {
    float2 best = smrg[tid];
    float zf = best.x;
    int twf = __float_as_int(best.y);
#pragma unroll
    for (int w8 = 1; w8 < 8; ++w8) {
      float2 c = smrg[w8 * 64 + tid];
      int tc = __float_as_int(c.y);
      bool win = (c.x > zf) | ((c.x == zf) & (tc > twf));
      zf = win ? c.x : zf;
      twf = win ? tc : twf;
    }
    float4 res = make_float4(0.0f, 0.0f, 0.0f, 0.0f);
    if (twf >= 0) {
      float4 f1 = lrec[twf * 4 + 1];   // v2x v2y r6 r7
      float4 f2 = lrec[twf * 4 + 2];   // v0x v0y r10 r11
      float4 f3 = lrec[twf * 4 + 3];   // rw v2z d0z d1z
      float pCB = __fsub_rn(__fmul_rn(__fsub_rn(px, f1.x), f1.z),
                            __fmul_rn(__fsub_rn(py, f1.y), f1.w));
      float pCA = __fsub_rn(__fmul_rn(__fsub_rn(px, f2.x), f2.z),
                            __fmul_rn(__fsub_rn(py, f2.y), f2.w));
      float w1 = __fmul_rn(pCB, f3.x);
      float w2 = __fmul_rn(pCA, f3.x);
      float rx = __fmaf_rn(w1, -f2.w, __fmaf_rn(w2, f1.w, f1.x));
      float ry = __fmaf_rn(w1, -f2.z, __fmaf_rn(w2, f1.z, f1.y));
      res = make_float4(rx, ry, zf, 1.0f);
    }
    out[((unsigned)i << 9) | (jw0 + (unsigned)tid)] = res;
  }
}

extern "C" void kernel_launch(void* const* d_in, const int* in_sizes, int n_in,
                              void* d_out, int out_size, void* d_ws, size_t ws_size,
                              hipStream_t stream) {
  const float* tris = (const float*)d_in[0];
  float4* out = (float4*)d_out;
  hipLaunchKernelGGL(render_fused, dim3(4096), dim3(512), 0, stream, tris, out);
}

// Round 13
// 70.783 us; speedup vs baseline: 1.8554x; 1.1089x over previous
//
#include <hip/hip_runtime.h>

#define TSIZE 512
#define NT 512
#define EPSV 1e-9f

// SINGLE fused kernel, half-row blocks. Grid = 1024 (row i = b>>1, jhalf = b&1
// covering 4 strips of 64 px), 512 threads = 8 waves.
//  1. stage raw tris (18 KB) into LDS.
//  2. thread t: record for tri t (R4 layout) -> LDS; AABB ints; ONE row-slice
//     y-interval (conservative, row-only); 4 per-strip window tests ->
//     4 __ballot -> 32 survivor words in LDS. zmin reduced in-block.
//  3. wave w: strip k=w>>1, tri-half h=w&1; pops words 4h..4h+3 (each survivor
//     fetched once per strip), lane = pixel, evals from LDS broadcasts,
//     tracks (zb, t_win). Per-strip x-test is exact in the cull.
//  4. 2-way lex-merge per strip (painter == lex-argmax(pz,t), R7-validated),
//     one exact winner interpolation, coalesced 256-px store.
// No workspace. Sign-determining chains bit-exact vs numpy (__f*_rn, same
// order, same single-rounded diffs as R4..R12); cull math conservative-only.

__device__ __forceinline__ float rcp_fast(float x) {
  float r;
  asm("v_rcp_f32 %0, %1" : "=v"(r) : "v"(x));
  return r;
}

__global__ __launch_bounds__(512) void render_fused(const float* __restrict__ tris,
                                                    float4* __restrict__ out) {
  __shared__ float4 lrec[NT * 4];             // 32 KB; first 18 KB doubles as raw stage
  __shared__ unsigned lbY[NT];                // 2 KB ym|yM<<16
  __shared__ float2 smrg[NT];                 // 4 KB merge
  __shared__ unsigned long long swords[32];   // 4 strips x 8 tri-words
  __shared__ float sred[8];

  const int tid = threadIdx.x;      // 0..511
  const int bb = blockIdx.x;        // 0..1023
  const int i = bb >> 1;            // row (block-uniform)
  const int jhalf = bb & 1;
  const unsigned jbase = (unsigned)(jhalf << 8);
  const float delta = 2.0f / 511.0f;

  // ---- 1. stage raw tris ----
  {
    const float4* g4 = (const float4*)tris;
    float4* rw4 = lrec;
    rw4[tid] = g4[tid];
    rw4[tid + 512] = g4[tid + 512];
    if (tid < 128) rw4[tid + 1024] = g4[tid + 1024];
  }
  __syncthreads();

  // ---- 2. per-tri record + row-slice cull + 4 strip ballots ----
  const float* rawf = (const float*)lrec;
  const float* tp = rawf + tid * 9;
  float v0x = tp[0], v0y = tp[1], v0z = tp[2];
  float v1x = tp[3], v1y = tp[4], v1z = tp[5];
  float v2x = tp[6], v2y = tp[7], v2z = tp[8];
  __syncthreads();   // raw values now in registers -> safe to overwrite lrec

  float w = __fsub_rn(__fmul_rn(__fsub_rn(v1x, v0x), __fsub_rn(v2y, v0y)),
                      __fmul_rn(__fsub_rn(v1y, v0y), __fsub_rn(v2x, v0x)));
  bool valid = (w >= EPSV);
  float ws = valid ? w : 1.0f;
  float r2  = __fsub_rn(v0y, v1y), r3  = __fsub_rn(v0x, v1x);
  float r6  = __fsub_rn(v1y, v2y), r7  = __fsub_rn(v1x, v2x);
  float r10 = __fsub_rn(v2y, v0y), r11 = __fsub_rn(v2x, v0x);

  int xmn = 0, xmx = 0, ymn = 0, ymx = 0;
  if (valid) {
    float bxn = fminf(v0x, fminf(v1x, v2x));
    float byn = fminf(v0y, fminf(v1y, v2y));
    float bxx = fmaxf(v0x, fmaxf(v1x, v2x));
    float byx = fmaxf(v0y, fmaxf(v1y, v2y));
    xmn = (int)floorf(__fmul_rn(__fadd_rn(fminf(fmaxf(bxn, -1.0f), 1.0f), 1.0f), 256.0f));
    ymn = (int)floorf(__fmul_rn(__fadd_rn(fminf(fmaxf(byn, -1.0f), 1.0f), 1.0f), 256.0f));
    xmx = (int)floorf(__fmul_rn(__fadd_rn(fminf(fmaxf(bxx, -1.0f), 1.0f), 1.0f), 256.0f));
    ymx = (int)floorf(__fmul_rn(__fadd_rn(fminf(fmaxf(byx, -1.0f), 1.0f), 1.0f), 256.0f));
  }

  // row-slice y-interval (row-only, computed once; conservative margins)
  const bool xpass = ((unsigned)i >= (unsigned)xmn) & ((unsigned)i < (unsigned)xmx);
  float ylo = -1e30f, yhi = 1e30f;
  if (xpass) {
    const float px_s = -1.0f + (float)i * delta;
    {
      float S = -r3, c = (v1y * r3 - v1x * r2) + r2 * px_s;
      if (S > 1e-20f)       { float cd = -c * rcp_fast(S); ylo = fmaxf(ylo, cd - (0.005f + 4e-6f * fabsf(cd))); }
      else if (S < -1e-20f) { float cd = -c * rcp_fast(S); yhi = fminf(yhi, cd + (0.005f + 4e-6f * fabsf(cd))); }
    }
    {
      float S = -r7, c = (v2y * r7 - v2x * r6) + r6 * px_s;
      if (S > 1e-20f)       { float cd = -c * rcp_fast(S); ylo = fmaxf(ylo, cd - (0.005f + 4e-6f * fabsf(cd))); }
      else if (S < -1e-20f) { float cd = -c * rcp_fast(S); yhi = fminf(yhi, cd + (0.005f + 4e-6f * fabsf(cd))); }
    }
    {
      float S = -r11, c = (v0y * r11 - v0x * r10) + r10 * px_s;
      if (S > 1e-20f)       { float cd = -c * rcp_fast(S); ylo = fmaxf(ylo, cd - (0.005f + 4e-6f * fabsf(cd))); }
      else if (S < -1e-20f) { float cd = -c * rcp_fast(S); yhi = fminf(yhi, cd + (0.005f + 4e-6f * fabsf(cd))); }
    }
  }

  // 4 per-strip ballots
#pragma unroll
  for (int k = 0; k < 4; ++k) {
    const unsigned jw0 = jbase + ((unsigned)k << 6);
    const float pyL = -1.0f + (float)jw0 * delta;
    const float pyR = -1.0f + (float)(jw0 + 63u) * delta;
    bool pk = xpass & ((unsigned)ymn < jw0 + 64u) & ((unsigned)ymx > jw0) &
              (ylo <= pyR) & (yhi >= pyL);
    unsigned long long wd = __ballot(pk ? 1 : 0);
    if ((tid & 63) == 0) swords[k * 8 + (tid >> 6)] = wd;
  }

  // records + ybnd + zmin
  lrec[tid * 4 + 0] = make_float4(v1x, v1y, r2, r3);
  lrec[tid * 4 + 1] = make_float4(v2x, v2y, r6, r7);
  lrec[tid * 4 + 2] = make_float4(v0x, v0y, r10, r11);
  lrec[tid * 4 + 3] = make_float4(__fdiv_rn(1.0f, ws), v2z,
                                  __fsub_rn(v0z, v2z), __fsub_rn(v1z, v2z));
  lbY[tid] = (unsigned)ymn | ((unsigned)ymx << 16);

  float zp = fminf(v0z, fminf(v1z, v2z));
  for (int off = 32; off > 0; off >>= 1) zp = fminf(zp, __shfl_down(zp, off, 64));
  if ((tid & 63) == 0) sred[tid >> 6] = zp;
  __syncthreads();
  float zm0 = sred[0];
#pragma unroll
  for (int kk = 1; kk < 8; ++kk) zm0 = fminf(zm0, sred[kk]);

  // ---- 3. eval: wave w = (strip w>>1, tri-half w&1); lane = pixel ----
  const int wv = tid >> 6;
  const int lane = tid & 63;
  const int k = wv >> 1;
  const int h = wv & 1;
  const unsigned ju = jbase + ((unsigned)k << 6) + (unsigned)lane;
  const float px = __fadd_rn(-1.0f, __fmul_rn((float)i, delta));
  const float py = __fadd_rn(-1.0f, __fmul_rn((float)ju, delta));

  float zb = zm0;
  int tw = -1;
#pragma unroll 1
  for (int q = 0; q < 4; ++q) {
    unsigned long long m = swords[k * 8 + h * 4 + q];
    const int tb = (h * 4 + q) << 6;
    while (m) {
      const int t = tb + __builtin_ctzll(m);
      m &= m - 1;
      float4 c0 = lrec[t * 4 + 0];
      float4 c1 = lrec[t * 4 + 1];
      float4 c2 = lrec[t * 4 + 2];
      float4 c3 = lrec[t * 4 + 3];
      unsigned yb = lbY[t];
      float pAB = __fsub_rn(__fmul_rn(__fsub_rn(px, c0.x), c0.z),
                            __fmul_rn(__fsub_rn(py, c0.y), c0.w));
      float pCB = __fsub_rn(__fmul_rn(__fsub_rn(px, c1.x), c1.z),
                            __fmul_rn(__fsub_rn(py, c1.y), c1.w));
      float pCA = __fsub_rn(__fmul_rn(__fsub_rn(px, c2.x), c2.z),
                            __fmul_rn(__fsub_rn(py, c2.y), c2.w));
      bool ins = (pAB > 0.0f) & (pCB > 0.0f) & (pCA > 0.0f) &
                 (ju >= (yb & 0xFFFFu)) & (ju < (yb >> 16));
      float w1 = __fmul_rn(pCB, c3.x);
      float w2 = __fmul_rn(pCA, c3.x);
      float pz = __fmaf_rn(w1, c3.z, __fmaf_rn(w2, c3.w, c3.y));
      bool mk = ins & (pz >= zb);
      zb = mk ? pz : zb;
      tw = mk ? t : tw;
    }
  }
  smrg[tid] = make_float2(zb, __int_as_float(tw));
  __syncthreads();

  // ---- 4. per-strip 2-way lex-merge + winner interp (threads 0..255) ----
  if (tid < 256) {
    const int ks = tid >> 6, l = tid & 63;
    float2 a = smrg[ks * 128 + l];         // tri-half 0 (ids 0..255)
    float2 b = smrg[ks * 128 + 64 + l];    // tri-half 1 (ids 256..511)
    int t0 = __float_as_int(a.y), t1 = __float_as_int(b.y);
    bool win1 = (b.x > a.x) | ((b.x == a.x) & (t1 > t0));
    int twf = win1 ? t1 : t0;
    float zf = win1 ? b.x : a.x;

    const unsigned ju2 = jbase + (unsigned)tid;
    const float py2 = __fadd_rn(-1.0f, __fmul_rn((float)ju2, delta));

    float4 res = make_float4(0.0f, 0.0f, 0.0f, 0.0f);
    if (twf >= 0) {
      float4 f1 = lrec[twf * 4 + 1];   // v2x v2y r6 r7
      float4 f2 = lrec[twf * 4 + 2];   // v0x v0y r10 r11
      float4 f3 = lrec[twf * 4 + 3];   // rw v2z d0z d1z
      float pCB = __fsub_rn(__fmul_rn(__fsub_rn(px, f1.x), f1.z),
                            __fmul_rn(__fsub_rn(py2, f1.y), f1.w));
      float pCA = __fsub_rn(__fmul_rn(__fsub_rn(px, f2.x), f2.z),
                            __fmul_rn(__fsub_rn(py2, f2.y), f2.w));
      float w1 = __fmul_rn(pCB, f3.x);
      float w2 = __fmul_rn(pCA, f3.x);
      float rx = __fmaf_rn(w1, -f2.w, __fmaf_rn(w2, f1.w, f1.x));
      float ry = __fmaf_rn(w1, -f2.z, __fmaf_rn(w2, f1.z, f1.y));
      res = make_float4(rx, ry, zf, 1.0f);
    }
    out[((unsigned)i << 9) | ju2] = res;
  }
}

extern "C" void kernel_launch(void* const* d_in, const int* in_sizes, int n_in,
                              void* d_out, int out_size, void* d_ws, size_t ws_size,
                              hipStream_t stream) {
  const float* tris = (const float*)d_in[0];
  float4* out = (float4*)d_out;
  hipLaunchKernelGGL(render_fused, dim3(1024), dim3(512), 0, stream, tris, out);
}